// Round 3
// baseline (1713.279 us; speedup 1.0000x reference)
//
#include <hip/hip_runtime.h>
#include <hip/hip_bf16.h>

typedef _Float16 half8 __attribute__((ext_vector_type(8)));
typedef _Float16 half4 __attribute__((ext_vector_type(4)));
typedef float    floatx4 __attribute__((ext_vector_type(4)));

#define B_TOT 4096
#define L_SEQ 2048
#define H_DIM 256
#define FUT   128
#define T_TOT (L_SEQ + FUT)   /* 2176 */
#define ROWS  16              /* batch rows per block */
#define CHUNK 256             /* x prefetch chunk (steps) */

// tanh(p) = 1 - 2/(e^{2p}+1).  No clamp needed: exp2->inf gives 1-0=1,
// exp2->0 gives 1-2=-1.  3 VALU + 2 trans.
__device__ __forceinline__ float tanh_fast(float p) {
    float e = __builtin_amdgcn_exp2f(p * 2.885390082f);     // e^(2p)
    return __builtin_fmaf(-2.0f, __builtin_amdgcn_rcpf(e + 1.0f), 1.0f);
}

// Swapped-operand step GEMM: C = W_tile(A) @ h^T(B).
//   A-frag: W[tile*16+ln15][kk*32+lg*8+j]  (loop-invariant registers)
//   B-frag: h[ln15][kk*32+lg*8+j]          (ds_read_b128, XOR-swizzled)
//   C-frag: col = ln15 = batch row; row = lg*4+r = output neuron within tile
// Single depth-8 MFMA chain per tile, init = fma(x_t, W_ih, b) (bias+input
// folded, no merge adds).  lin(h) = 17th tile on wave 0.  Outputs ring-buffer
// in LDS, coalesced global flush every 32 steps.
__global__ __launch_bounds__(512, 2) void rnn_seq_kernel(
    const float* __restrict__ x,      // [B, L]
    const float* __restrict__ W_ih,   // [H]
    const float* __restrict__ b_ih,   // [H]
    const float* __restrict__ W_hh,   // [H, H]
    const float* __restrict__ b_hh,   // [H]
    const float* __restrict__ W_lin,  // [H]
    const float* __restrict__ b_lin,  // [1]
    float* __restrict__ out)          // [B, T_TOT]
{
    __shared__ __align__(16) unsigned char hbuf[2][ROWS * H_DIM * 2]; // fp16 dbuf
    __shared__ __align__(16) float xbuf[CHUNK * 17];                  // [t_local][row] padded
    __shared__ __align__(16) float obuf2[2][32][17];                  // out ring, padded

    const int tid  = threadIdx.x;
    const int l    = tid & 63;
    const int w    = tid >> 6;       // wave 0..7
    const int ln15 = l & 15;
    const int lg   = l >> 4;         // 0..3
    const int b0   = blockIdx.x * ROWS;

    // ---- loop-invariant register state ----
    half8 wf[2][8];                   // W_hh A-frags: 2 N-tiles per wave
    #pragma unroll
    for (int i = 0; i < 2; ++i) {
        const int n = (2 * w + i) * 16 + ln15;
        #pragma unroll
        for (int kk = 0; kk < 8; ++kk) {
            const float* p = W_hh + n * H_DIM + kk * 32 + lg * 8;
            half8 v;
            #pragma unroll
            for (int j = 0; j < 8; ++j) v[j] = (_Float16)p[j];
            wf[i][kk] = v;
        }
    }
    half8 wlf[8];                     // W_lin A-frag (row 0), wave 0 only
    #pragma unroll
    for (int kk = 0; kk < 8; ++kk) {
        const int kbase = kk * 32 + lg * 8;
        half8 v;
        #pragma unroll
        for (int j = 0; j < 8; ++j)
            v[j] = (ln15 == 0) ? (_Float16)W_lin[kbase + j] : (_Float16)0.0f;
        wlf[kk] = v;
    }
    floatx4 wih4[2], bia4[2];
    #pragma unroll
    for (int i = 0; i < 2; ++i) {
        const int n0 = (2 * w + i) * 16 + lg * 4;
        #pragma unroll
        for (int r = 0; r < 4; ++r) {
            wih4[i][r] = W_ih[n0 + r];
            bia4[i][r] = b_ih[n0 + r] + b_hh[n0 + r];
        }
    }
    const float blin = b_lin[0];
    float wl[8];                      // final lin after the loop
    #pragma unroll
    for (int j = 0; j < 8; ++j) wl[j] = W_lin[(tid & 31) * 8 + j];

    // LDS byte offsets (XOR swizzle bits 4-6 keyed by row m&7)
    int aoff[8];
    #pragma unroll
    for (int kk = 0; kk < 8; ++kk)
        aoff[kk] = (ln15 * 512 + kk * 64 + lg * 16) ^ ((ln15 & 7) << 4);
    int woff2[2];
    #pragma unroll
    for (int i = 0; i < 2; ++i)
        woff2[i] = (ln15 * 512 + (2 * w + i) * 32 + lg * 8) ^ ((ln15 & 7) << 4);

    *(floatx4*)(hbuf[0] + tid * 16) = floatx4{0.f, 0.f, 0.f, 0.f};  // h0 = 0
    __syncthreads();

    int cur = 0;
    for (int s = 1; s <= T_TOT; ++s) {
        const int t_out = s - 2;      // out index produced by this step

        // coalesced flush of the completed 32-out block (opposite ring half;
        // the global store drains under this whole step before next barrier)
        if (t_out >= 32 && (t_out & 31) == 0) {
            const int tb = t_out - 32, par = (tb >> 5) & 1;
            const int row = tid >> 5, tt = tid & 31;
            out[(size_t)(b0 + row) * T_TOT + tb + tt] = obuf2[par][tt][row] + blin;
        }

        const bool fut = (s > L_SEQ);
        float xm = 0.0f;
        if (!fut) {
            if (((s - 1) & (CHUNK - 1)) == 0) {          // x chunk prefetch
                #pragma unroll
                for (int jj = 0; jj < 8; ++jj) {
                    const int idx = jj * 512 + tid;
                    const int row = idx >> 8, tl = idx & 255;
                    xbuf[tl * 17 + row] = x[(size_t)(b0 + row) * L_SEQ + (s - 1) + tl];
                }
                __syncthreads();
            }
            xm = xbuf[((s - 1) & (CHUNK - 1)) * 17 + ln15];
        }

        // B-frags of h_{s-1}
        half8 a[8];
        #pragma unroll
        for (int kk = 0; kk < 8; ++kk)
            a[kk] = *(const half8*)(hbuf[cur] + aoff[kk]);

        // single depth-8 chain per tile; main phase folds bias + x*W_ih into init
        floatx4 acc[2];
        #pragma unroll
        for (int i = 0; i < 2; ++i) {
            #pragma unroll
            for (int r = 0; r < 4; ++r)
                acc[i][r] = fut ? bia4[i][r]
                                : __builtin_fmaf(xm, wih4[i][r], bia4[i][r]);
        }
        #pragma unroll
        for (int kk = 0; kk < 8; ++kk) {
            acc[0] = __builtin_amdgcn_mfma_f32_16x16x32_f16(wf[0][kk], a[kk], acc[0], 0, 0, 0);
            acc[1] = __builtin_amdgcn_mfma_f32_16x16x32_f16(wf[1][kk], a[kk], acc[1], 0, 0, 0);
        }
        // lin tile (wave 0): C row 0 = lin(h_{s-1}) = out[s-2] (sans b_lin)
        if (w == 0) {
            floatx4 al = floatx4{0, 0, 0, 0};
            #pragma unroll
            for (int kk = 0; kk < 8; ++kk)
                al = __builtin_amdgcn_mfma_f32_16x16x32_f16(wlf[kk], a[kk], al, 0, 0, 0);
            if (lg == 0 && s >= 2)
                obuf2[(t_out >> 5) & 1][t_out & 31][ln15] = al[0];
        }

        if (fut) {
            __syncthreads();          // this step's lin visible to all waves
            xm = obuf2[(t_out >> 5) & 1][t_out & 31][ln15] + blin;
        }

        // epilogue: tanh + packed b64 h-write
        #pragma unroll
        for (int i = 0; i < 2; ++i) {
            half4 hv;
            #pragma unroll
            for (int r = 0; r < 4; ++r) {
                const float pre = fut ? __builtin_fmaf(xm, wih4[i][r], acc[i][r])
                                      : acc[i][r];
                hv[r] = (_Float16)tanh_fast(pre);
            }
            *(half4*)(hbuf[cur ^ 1] + woff2[i]) = hv;
        }
        __syncthreads();
        cur ^= 1;
    }

    // final out: t = 2175 = lin(h_final) -> ring slot [1][31]
    {
        const int m = tid >> 5, kb = (tid & 31) * 8;
        const int off = (m * 512 + kb * 2) ^ ((m & 7) << 4);
        const half8 hv = *(const half8*)(hbuf[cur] + off);
        float dot = 0.f;
        #pragma unroll
        for (int j = 0; j < 8; ++j) dot += (float)hv[j] * wl[j];
        #pragma unroll
        for (int msk = 1; msk < 32; msk <<= 1) dot += __shfl_xor(dot, msk, 32);
        if ((tid & 31) == 0) obuf2[1][31][m] = dot;
    }
    __syncthreads();
    {   // final flush t = 2144..2175
        const int row = tid >> 5, tt = tid & 31;
        out[(size_t)(b0 + row) * T_TOT + 2144 + tt] = obuf2[1][tt][row] + blin;
    }
}

extern "C" void kernel_launch(void* const* d_in, const int* in_sizes, int n_in,
                              void* d_out, int out_size, void* d_ws, size_t ws_size,
                              hipStream_t stream) {
    const float* x     = (const float*)d_in[0];
    const float* W_ih  = (const float*)d_in[1];
    const float* b_ih  = (const float*)d_in[2];
    const float* W_hh  = (const float*)d_in[3];
    const float* b_hh  = (const float*)d_in[4];
    const float* W_lin = (const float*)d_in[5];
    const float* b_lin = (const float*)d_in[6];
    float* out = (float*)d_out;
    rnn_seq_kernel<<<B_TOT / ROWS, 512, 0, stream>>>(x, W_ih, b_ih, W_hh, b_hh, W_lin, b_lin, out);
}